// Round 3
// baseline (88.387 us; speedup 1.0000x reference)
//
#include <hip/hip_runtime.h>

#define CIN 27
#define HH 64
#define WW 64
#define OC 32
#define TW 16   // tile width in pixels
#define TH 16   // tile height in pixels
// block: 8 x 16 = 128 threads; each thread computes 2 horizontally-adjacent pixels

__device__ __forceinline__ float2 pk_maj3(float2 a, float2 b, float2 c) {
    // maj3(a,b,c) = (a+b+c - a*b*c)/2, applied to both packed lanes
    float2 r;
    r.x = 0.5f * (a.x + b.x + c.x - a.x * b.x * c.x);
    r.y = 0.5f * (a.y + b.y + c.y - a.y * b.y * c.y);
    return r;
}

__global__ __launch_bounds__(128) void sconv_maj_kernel(
    const float* __restrict__ x,    // [N, CIN, 64, 64]
    const float* __restrict__ wgt,  // [OC, CIN, 3, 3]
    float* __restrict__ out)        // [N, OC, 64, 64]
{
    __shared__ float sx[CIN][TH + 2][TW + 2];  // 27*18*18*4 = 34992 B

    const int tx = threadIdx.x;            // 0..7  (pixel cols 2tx, 2tx+1)
    const int ty = threadIdx.y;            // 0..15
    const int tid = ty * 8 + tx;
    const int tile_w0 = blockIdx.x * TW;
    const int tile_h0 = blockIdx.y * TH;
    const int n  = blockIdx.z >> 5;        // OC = 32
    const int oc = blockIdx.z & 31;

    // ---- stage x tile with 1-halo, zero padding (scalar, coalesced-ish) ----
    const int TOT = CIN * (TH + 2) * (TW + 2);  // 8748
    const float* xn = x + (size_t)n * (CIN * HH * WW);
    for (int idx = tid; idx < TOT; idx += 128) {
        int c   = idx / ((TH + 2) * (TW + 2));
        int rem = idx - c * ((TH + 2) * (TW + 2));
        int r   = rem / (TW + 2);
        int col = rem - r * (TW + 2);
        int gr = tile_h0 + r - 1;
        int gc = tile_w0 + col - 1;
        float v = 0.0f;
        if (gr >= 0 && gr < HH && gc >= 0 && gc < WW)
            v = xn[c * (HH * WW) + gr * WW + gc];
        ((float*)sx)[idx] = v;
    }
    __syncthreads();

    // ---- weights: block-uniform address -> scalar (s_load) path, no LDS ----
    const float* __restrict__ wb = wgt + oc * (CIN * 9);

    // ---- 5-level majority tree, 2 pixels per thread (packed float2) ----
    float2 m2[CIN];
    #pragma unroll
    for (int c = 0; c < CIN; ++c) {
        float2 m1[3];
        #pragma unroll
        for (int ki = 0; ki < 3; ++ki) {
            // row base offset (c*324 + r*18 floats) is even -> float2-aligned
            const float2* prow = (const float2*)(&sx[c][ty + ki][0]);
            float2 v01 = prow[tx];       // cols 2tx,   2tx+1
            float2 v23 = prow[tx + 1];   // cols 2tx+2, 2tx+3
            float w0 = wb[c * 9 + ki * 3 + 0];
            float w1 = wb[c * 9 + ki * 3 + 1];
            float w2 = wb[c * 9 + ki * 3 + 2];
            // pixel A (col 2tx) uses cols 2tx..2tx+2; pixel B uses 2tx+1..2tx+3
            float2 p0 = make_float2(v01.x * w0, v01.y * w0);
            float2 p1 = make_float2(v01.y * w1, v23.x * w1);
            float2 p2 = make_float2(v23.x * w2, v23.y * w2);
            m1[ki] = pk_maj3(p0, p1, p2);
        }
        m2[c] = pk_maj3(m1[0], m1[1], m1[2]);
    }
    float2 m3[9];
    #pragma unroll
    for (int g = 0; g < 9; ++g)
        m3[g] = pk_maj3(m2[3 * g], m2[3 * g + 1], m2[3 * g + 2]);
    float2 m4a = pk_maj3(m3[0], m3[1], m3[2]);
    float2 m4b = pk_maj3(m3[3], m3[4], m3[5]);
    float2 m4c = pk_maj3(m3[6], m3[7], m3[8]);
    float2 res = pk_maj3(m4a, m4b, m4c);

    const int h = tile_h0 + ty;
    const int w = tile_w0 + 2 * tx;
    // (row*64 + even col) -> 8B-aligned float2 store, coalesced across lanes
    float2* po = (float2*)(out + (((size_t)n * OC + oc) * HH + h) * WW + w);
    *po = res;
}

extern "C" void kernel_launch(void* const* d_in, const int* in_sizes, int n_in,
                              void* d_out, int out_size, void* d_ws, size_t ws_size,
                              hipStream_t stream) {
    const float* x   = (const float*)d_in[0];
    const float* wgt = (const float*)d_in[1];
    float* out = (float*)d_out;

    dim3 block(8, 16, 1);                 // 128 threads, 2 waves
    dim3 grid(WW / TW, HH / TH, 2 * OC);  // (4, 4, 64) = 1024 blocks
    sconv_maj_kernel<<<grid, block, 0, stream>>>(x, wgt, out);
}

// Round 4
// 77.837 us; speedup vs baseline: 1.1356x; 1.1356x over previous
//
#include <hip/hip_runtime.h>

#define CIN 27
#define HH 64
#define WW 64
#define OC 32
#define TW 16            // tile width (pixels)
#define TH 16            // tile height (pixels)
#define RS 19            // padded LDS row stride in dwords (18 used + 1 pad -> <=2-way banks)
#define CS (18 * RS)     // per-channel slab stride = 342 dwords
#define WS 12            // padded per-channel weight stride (16B aligned)

__device__ __forceinline__ float maj3(float a, float b, float c) {
    // Exact closed form of the bipolar 3-input majority-gate simulation:
    // maj3 = (a + b + c - a*b*c) / 2
    float s = a + b + c;
    float p = a * b;
    return 0.5f * fmaf(-p, c, s);
}

__device__ __forceinline__ float2 pk_maj3(float2 a, float2 b, float2 c) {
    float2 r;
    r.x = maj3(a.x, b.x, c.x);
    r.y = maj3(a.y, b.y, c.y);
    return r;
}

__global__ __launch_bounds__(128) void sconv_maj_kernel(
    const float* __restrict__ x,    // [N, CIN, 64, 64]
    const float* __restrict__ wgt,  // [OC, CIN, 3, 3]
    float* __restrict__ out)        // [N, OC, 64, 64]
{
    __shared__ __align__(16) float sw[CIN * WS];  // 1296 B, padded 9->12 per channel
    __shared__ float sx[CIN * CS];                // 27*342*4 = 36936 B

    const int tx = threadIdx.x;            // 0..7  (pixel cols 2tx, 2tx+1)
    const int ty = threadIdx.y;            // 0..15
    const int tid = ty * 8 + tx;
    const int tile_w0 = blockIdx.x * TW;
    const int tile_h0 = blockIdx.y * TH;
    const int n  = blockIdx.z >> 5;        // OC = 32
    const int oc = blockIdx.z & 31;

    // ---- stage weights (block-uniform oc) into padded LDS slots ----
    for (int i = tid; i < CIN * 9; i += 128) {
        int c = i / 9;
        int k = i - 9 * c;
        sw[c * WS + k] = wgt[oc * (CIN * 9) + i];
    }

    // ---- stage x tile with 1-halo: decode (r,col) once, stride over c ----
    const float* xn = x + (size_t)n * (CIN * HH * WW);
    for (int pos = tid; pos < 18 * 18; pos += 128) {
        int r   = pos / 18;
        int col = pos - 18 * r;
        int gr = tile_h0 + r - 1;
        int gc = tile_w0 + col - 1;
        bool ok = (gr >= 0 && gr < HH && gc >= 0 && gc < WW);
        const float* gp = xn + gr * WW + gc;
        float* lp = sx + r * RS + col;
        #pragma unroll
        for (int c = 0; c < CIN; ++c) {
            lp[c * CS] = ok ? gp[c * (HH * WW)] : 0.0f;
        }
    }
    __syncthreads();

    // ---- 5-level majority tree, 2 horizontally-adjacent pixels / thread ----
    float2 m2[CIN];
    #pragma unroll
    for (int c = 0; c < CIN; ++c) {
        // 9 weights via two 16B broadcast reads + scalar (padded, aligned)
        float4 wa = *(const float4*)&sw[c * WS];      // w0..w3
        float4 wb = *(const float4*)&sw[c * WS + 4];  // w4..w7
        float  w8 = sw[c * WS + 8];
        const float wk[9] = {wa.x, wa.y, wa.z, wa.w, wb.x, wb.y, wb.z, wb.w, w8};

        float2 m1[3];
        #pragma unroll
        for (int ki = 0; ki < 3; ++ki) {
            const float* row = &sx[c * CS + (ty + ki) * RS + 2 * tx];
            float v0 = row[0], v1 = row[1], v2 = row[2], v3 = row[3];
            float w0 = wk[ki * 3 + 0], w1 = wk[ki * 3 + 1], w2 = wk[ki * 3 + 2];
            // pixel A (col 2tx): v0,v1,v2 ; pixel B (col 2tx+1): v1,v2,v3
            float2 p0 = make_float2(v0 * w0, v1 * w0);
            float2 p1 = make_float2(v1 * w1, v2 * w1);
            float2 p2 = make_float2(v2 * w2, v3 * w2);
            m1[ki] = pk_maj3(p0, p1, p2);
        }
        m2[c] = pk_maj3(m1[0], m1[1], m1[2]);
    }
    float2 m3[9];
    #pragma unroll
    for (int g = 0; g < 9; ++g)
        m3[g] = pk_maj3(m2[3 * g], m2[3 * g + 1], m2[3 * g + 2]);
    float2 m4a = pk_maj3(m3[0], m3[1], m3[2]);
    float2 m4b = pk_maj3(m3[3], m3[4], m3[5]);
    float2 m4c = pk_maj3(m3[6], m3[7], m3[8]);
    float2 res = pk_maj3(m4a, m4b, m4c);

    const int h = tile_h0 + ty;
    const int w = tile_w0 + 2 * tx;
    float2* po = (float2*)(out + (((size_t)n * OC + oc) * HH + h) * WW + w);
    *po = res;
}

extern "C" void kernel_launch(void* const* d_in, const int* in_sizes, int n_in,
                              void* d_out, int out_size, void* d_ws, size_t ws_size,
                              hipStream_t stream) {
    const float* x   = (const float*)d_in[0];
    const float* wgt = (const float*)d_in[1];
    float* out = (float*)d_out;

    dim3 block(8, 16, 1);                 // 128 threads, 2 waves
    dim3 grid(WW / TW, HH / TH, 2 * OC);  // (4, 4, 64) = 1024 blocks, 4/CU
    sconv_maj_kernel<<<grid, block, 0, stream>>>(x, wgt, out);
}